// Round 1
// baseline (263.528 us; speedup 1.0000x reference)
//
#include <hip/hip_runtime.h>
#include <hip/hip_bf16.h>
#include <cmath>

#define BATCH 4
#define SEQ 2048
#define DM 1024
#define NS 16
#define M_ROWS (BATCH * SEQ)

typedef short bf16x8 __attribute__((ext_vector_type(8)));
typedef float f32x4 __attribute__((ext_vector_type(4)));

// fp32 -> bf16 round-to-nearest-even (inputs are finite; no NaN handling needed)
__device__ __forceinline__ short f2bf(float f) {
    union { float f; unsigned u; } a; a.f = f;
    unsigned u = a.u;
    unsigned r = (u + 0x7fffu + ((u >> 16) & 1u)) >> 16;
    return (short)r;
}

// ---------------------------------------------------------------------------
// Kernel 1: bc[m] = sum_n (x_row . W2_n + b2_n) * (x_row . W3_n + b3_n)
// One block (256 thr) per row. fp32 throughout.
// ---------------------------------------------------------------------------
__global__ void __launch_bounds__(256) bc_kernel(
    const float* __restrict__ x,
    const float* __restrict__ W2, const float* __restrict__ b2,
    const float* __restrict__ W3, const float* __restrict__ b3,
    float* __restrict__ bc)
{
    __shared__ float xs[DM];
    __shared__ float parts[NS];
    const int m = blockIdx.x;
    const int t = threadIdx.x;
    const int lane = t & 63;
    const int w = t >> 6;

    for (int i = t; i < DM; i += 256) xs[i] = x[(size_t)m * DM + i];
    __syncthreads();

    for (int n = w; n < NS; n += 4) {
        float pb = 0.f, pc = 0.f;
        const float* w2r = W2 + (size_t)n * DM;
        const float* w3r = W3 + (size_t)n * DM;
        for (int k = lane; k < DM; k += 64) {
            float xv = xs[k];
            pb += xv * w2r[k];
            pc += xv * w3r[k];
        }
        #pragma unroll
        for (int off = 32; off > 0; off >>= 1) {
            pb += __shfl_down(pb, off);
            pc += __shfl_down(pc, off);
        }
        if (lane == 0) parts[n] = (pb + b2[n]) * (pc + b3[n]);
    }
    __syncthreads();
    if (t == 0) {
        float s = 0.f;
        #pragma unroll
        for (int n = 0; n < NS; n++) s += parts[n];
        bc[m] = s;
    }
}

// ---------------------------------------------------------------------------
// Kernel 2: fused z = x @ W1^T (bf16 MFMA, 128x128 tile, BK=32),
// epilogue y = x * softplus(z + b1) * bc[m]
// Both x and W1 are row-major with K contiguous (B^T GEMM form).
// ---------------------------------------------------------------------------
__global__ void __launch_bounds__(256) gemm_fused(
    const float* __restrict__ x, const float* __restrict__ W1,
    const float* __restrict__ b1, const float* __restrict__ bc,
    float* __restrict__ out)
{
    __shared__ short As[128][32];   // x tile,  [m][k] bf16 bits
    __shared__ short Bs[128][32];   // W1 tile, [n][k] bf16 bits

    const int n0 = blockIdx.x * 128;
    const int m0 = blockIdx.y * 128;
    const int t = threadIdx.x;
    const int lane = t & 63;
    const int w = t >> 6;
    const int wm = (w >> 1) * 64;    // wave's m offset in tile
    const int wn = (w & 1) * 64;     // wave's n offset in tile
    const int lm = lane & 15;
    const int quad = lane >> 4;
    const int ko = quad * 8;

    f32x4 acc[4][4] = {};

    for (int k0 = 0; k0 < DM; k0 += 32) {
        // ---- stage 128x32 fp32 -> bf16 into LDS (A and B tiles) ----
        #pragma unroll
        for (int i = 0; i < 4; i++) {
            int f = t + i * 256;          // 0..1023
            int row = f >> 3;             // 0..127
            int c4 = (f & 7) * 4;         // 0,4,...,28
            float4 va = *(const float4*)(x  + (size_t)(m0 + row) * DM + k0 + c4);
            float4 vb = *(const float4*)(W1 + (size_t)(n0 + row) * DM + k0 + c4);
            short4 sa = make_short4(f2bf(va.x), f2bf(va.y), f2bf(va.z), f2bf(va.w));
            short4 sb = make_short4(f2bf(vb.x), f2bf(vb.y), f2bf(vb.z), f2bf(vb.w));
            *(short4*)&As[row][c4] = sa;
            *(short4*)&Bs[row][c4] = sb;
        }
        __syncthreads();

        // ---- fragments: A[m=lane&15][k=quad*8+j], B[n=lane&15][k=quad*8+j] ----
        bf16x8 af[4], bfr[4];
        #pragma unroll
        for (int i = 0; i < 4; i++) {
            af[i]  = *(const bf16x8*)&As[wm + i * 16 + lm][ko];
            bfr[i] = *(const bf16x8*)&Bs[wn + i * 16 + lm][ko];
        }
        #pragma unroll
        for (int i = 0; i < 4; i++)
            #pragma unroll
            for (int j = 0; j < 4; j++)
                acc[i][j] = __builtin_amdgcn_mfma_f32_16x16x32_bf16(
                    af[i], bfr[j], acc[i][j], 0, 0, 0);
        __syncthreads();
    }

    // ---- epilogue: D layout col = lane&15 (n), row = quad*4 + r (m) ----
    #pragma unroll
    for (int i = 0; i < 4; i++) {
        #pragma unroll
        for (int r = 0; r < 4; r++) {
            int gm = m0 + wm + i * 16 + quad * 4 + r;
            float bcv = bc[gm];
            #pragma unroll
            for (int j = 0; j < 4; j++) {
                int gn = n0 + wn + j * 16 + lm;
                float z = acc[i][j][r] + b1[gn];
                // stable softplus: log1p(exp(-|z|)) + max(z,0)
                float sp = (z > 0.f) ? z + log1pf(expf(-z)) : log1pf(expf(z));
                size_t idx = (size_t)gm * DM + gn;
                out[idx] = x[idx] * sp * bcv;
            }
        }
    }
}

extern "C" void kernel_launch(void* const* d_in, const int* in_sizes, int n_in,
                              void* d_out, int out_size, void* d_ws, size_t ws_size,
                              hipStream_t stream) {
    const float* x  = (const float*)d_in[0];
    const float* W1 = (const float*)d_in[1];
    const float* b1 = (const float*)d_in[2];
    const float* W2 = (const float*)d_in[3];
    const float* b2 = (const float*)d_in[4];
    const float* W3 = (const float*)d_in[5];
    const float* b3 = (const float*)d_in[6];
    // d_in[7] = A is dead math (multiplied by zero state in the reference)
    float* out = (float*)d_out;
    float* bc  = (float*)d_ws;   // 8192 floats = 32 KB scratch

    bc_kernel<<<M_ROWS, 256, 0, stream>>>(x, W2, b2, W3, b3, bc);

    dim3 grid(DM / 128, M_ROWS / 128);   // (8, 64) = 512 blocks
    gemm_fused<<<grid, 256, 0, stream>>>(x, W1, b1, bc, out);
}

// Round 2
// 204.349 us; speedup vs baseline: 1.2896x; 1.2896x over previous
//
#include <hip/hip_runtime.h>
#include <hip/hip_bf16.h>
#include <cmath>

#define BATCH 4
#define SEQ 2048
#define DM 1024
#define NS 16
#define M_ROWS (BATCH * SEQ)

typedef short bf16x8 __attribute__((ext_vector_type(8)));
typedef short bf16x4 __attribute__((ext_vector_type(4)));
typedef float f32x4 __attribute__((ext_vector_type(4)));

// fp32 -> bf16 round-to-nearest-even
__device__ __forceinline__ short f2bf(float f) {
    union { float f; unsigned u; } a; a.f = f;
    unsigned u = a.u;
    return (short)((u + 0x7fffu + ((u >> 16) & 1u)) >> 16);
}

#define LDS_CAST(p) ((__attribute__((address_space(3))) unsigned*)(p))
#define GLB_CAST(p) ((const __attribute__((address_space(1))) unsigned*)(p))

// ---------------------------------------------------------------------------
// Kernel 0: convert x, W1, W2, W3 fp32 -> bf16 (vectorized, grid-stride).
// Wcb = [W2 rows 0..15 ; W3 rows 0..15], row-major K-contiguous.
// ---------------------------------------------------------------------------
__global__ void __launch_bounds__(256) convert_all(
    const float* __restrict__ x,  const float* __restrict__ W1,
    const float* __restrict__ W2, const float* __restrict__ W3,
    short* __restrict__ xb, short* __restrict__ W1b, short* __restrict__ Wcb)
{
    const int NX4  = M_ROWS * DM / 4;   // 2,097,152 quads
    const int NW14 = DM * DM / 4;       //   262,144
    const int NW24 = NS * DM / 4;       //     4,096
    const int total = NX4 + NW14 + 2 * NW24;
    for (int q = blockIdx.x * 256 + threadIdx.x; q < total; q += gridDim.x * 256) {
        const float* src; short* dst; int idx;
        if (q < NX4)                    { src = x;  dst = xb;            idx = q; }
        else if (q < NX4 + NW14)        { src = W1; dst = W1b;           idx = q - NX4; }
        else if (q < NX4 + NW14 + NW24) { src = W2; dst = Wcb;           idx = q - NX4 - NW14; }
        else                            { src = W3; dst = Wcb + NS * DM; idx = q - NX4 - NW14 - NW24; }
        float4 v = ((const float4*)src)[idx];
        bf16x4 s;
        s.x = f2bf(v.x); s.y = f2bf(v.y); s.z = f2bf(v.z); s.w = f2bf(v.w);
        ((bf16x4*)dst)[idx] = s;
    }
}

// ---------------------------------------------------------------------------
// Kernel 1: bc[m] = sum_n (B[m][n]+b2[n]) * (C[m][n]+b3[n]) via bf16 MFMA.
// [B | C] = xb @ Wcb^T  (M=8192, N=32, K=1024). 64-row tiles, 128 blocks.
// ---------------------------------------------------------------------------
__global__ void __launch_bounds__(256) bc_mfma(
    const short* __restrict__ xb, const short* __restrict__ Wcb,
    const float* __restrict__ b2, const float* __restrict__ b3,
    float* __restrict__ bc)
{
    __shared__ short xs[64][64];   // 8 KB, [m][k]
    const int m0 = blockIdx.x * 64;
    const int t = threadIdx.x;
    const int lane = t & 63;
    const int w = t >> 6;
    const int lm = lane & 15;
    const int quad = lane >> 4;

    f32x4 acc[2] = {};   // [j]: j=0 -> B (W2), j=1 -> C (W3)

    for (int k0 = 0; k0 < DM; k0 += 64) {
        #pragma unroll
        for (int u = 0; u < 2; u++) {
            int row = u * 32 + (t >> 3);      // 0..63
            int ke  = (t & 7) * 8;            // element offset in k
            const short* g = xb + (size_t)(m0 + row) * DM + k0 + ke;
            __builtin_amdgcn_global_load_lds(GLB_CAST(g), LDS_CAST(&xs[row][ke]), 16, 0, 0);
        }
        __syncthreads();
        #pragma unroll
        for (int ks = 0; ks < 2; ks++) {
            bf16x8 af = *(const bf16x8*)&xs[w * 16 + lm][ks * 32 + quad * 8];
            #pragma unroll
            for (int j = 0; j < 2; j++) {
                bf16x8 bfv = *(const bf16x8*)(Wcb + (size_t)(j * 16 + lm) * DM + k0 + ks * 32 + quad * 8);
                acc[j] = __builtin_amdgcn_mfma_f32_16x16x32_bf16(af, bfv, acc[j], 0, 0, 0);
            }
        }
        __syncthreads();
    }

    // D layout: col(n) = lane&15, row(m) = quad*4 + r
    float bb2 = b2[lm], bb3 = b3[lm];
    #pragma unroll
    for (int r = 0; r < 4; r++) {
        float p = (acc[0][r] + bb2) * (acc[1][r] + bb3);
        p += __shfl_xor(p, 1);
        p += __shfl_xor(p, 2);
        p += __shfl_xor(p, 4);
        p += __shfl_xor(p, 8);
        if (lm == 0) bc[m0 + w * 16 + quad * 4 + r] = p;
    }
}

// ---------------------------------------------------------------------------
// Kernel 2: z = xb @ W1b^T via MFMA (128x128 tile, BK=32, global_load_lds
// staging), epilogue y = x * softplus(z + b1) * bc[m].
// ---------------------------------------------------------------------------
__global__ void __launch_bounds__(256) gemm_fused(
    const short* __restrict__ xb, const short* __restrict__ W1b,
    const float* __restrict__ x,  const float* __restrict__ b1,
    const float* __restrict__ bc, float* __restrict__ out)
{
    __shared__ short As[128][32];   // x tile,  [m][k]
    __shared__ short Bs[128][32];   // W1 tile, [n][k]

    const int n0 = blockIdx.x * 128;
    const int m0 = blockIdx.y * 128;
    const int t = threadIdx.x;
    const int lane = t & 63;
    const int w = t >> 6;
    const int wm = (w >> 1) * 64;
    const int wn = (w & 1) * 64;
    const int lm = lane & 15;
    const int quad = lane >> 4;
    const int ko = quad * 8;

    f32x4 acc[4][4] = {};

    for (int k0 = 0; k0 < DM; k0 += 32) {
        // stage: 2 issues of 64 rows x 32k each for A and B (16 B/lane)
        #pragma unroll
        for (int u = 0; u < 2; u++) {
            int row = u * 64 + (t >> 2);      // 0..127
            int ke  = (t & 3) * 8;            // 0,8,16,24
            const short* ga = xb  + (size_t)(m0 + row) * DM + k0 + ke;
            const short* gb = W1b + (size_t)(n0 + row) * DM + k0 + ke;
            __builtin_amdgcn_global_load_lds(GLB_CAST(ga), LDS_CAST(&As[row][ke]), 16, 0, 0);
            __builtin_amdgcn_global_load_lds(GLB_CAST(gb), LDS_CAST(&Bs[row][ke]), 16, 0, 0);
        }
        __syncthreads();

        bf16x8 af[4], bfr[4];
        #pragma unroll
        for (int i = 0; i < 4; i++) {
            af[i]  = *(const bf16x8*)&As[wm + i * 16 + lm][ko];
            bfr[i] = *(const bf16x8*)&Bs[wn + i * 16 + lm][ko];
        }
        #pragma unroll
        for (int i = 0; i < 4; i++)
            #pragma unroll
            for (int j = 0; j < 4; j++)
                acc[i][j] = __builtin_amdgcn_mfma_f32_16x16x32_bf16(
                    af[i], bfr[j], acc[i][j], 0, 0, 0);
        __syncthreads();
    }

    // epilogue: D col(n)=lane&15, row(m)=quad*4+r
    #pragma unroll
    for (int i = 0; i < 4; i++) {
        #pragma unroll
        for (int r = 0; r < 4; r++) {
            int gm = m0 + wm + i * 16 + quad * 4 + r;
            float bcv = bc[gm];
            #pragma unroll
            for (int j = 0; j < 4; j++) {
                int gn = n0 + wn + j * 16 + lm;
                float z = acc[i][j][r] + b1[gn];
                float sp = (z > 0.f) ? z + log1pf(expf(-z)) : log1pf(expf(z));
                size_t idx = (size_t)gm * DM + gn;
                out[idx] = x[idx] * sp * bcv;
            }
        }
    }
}

extern "C" void kernel_launch(void* const* d_in, const int* in_sizes, int n_in,
                              void* d_out, int out_size, void* d_ws, size_t ws_size,
                              hipStream_t stream) {
    const float* x  = (const float*)d_in[0];
    const float* W1 = (const float*)d_in[1];
    const float* b1 = (const float*)d_in[2];
    const float* W2 = (const float*)d_in[3];
    const float* b2 = (const float*)d_in[4];
    const float* W3 = (const float*)d_in[5];
    const float* b3 = (const float*)d_in[6];
    // d_in[7] = A is dead math
    float* out = (float*)d_out;

    // workspace layout (bytes):
    //   xb  : 8192*1024*2 = 16 MiB   @ 0
    //   W1b : 1024*1024*2 =  2 MiB   @ 16 MiB
    //   Wcb : 32*1024*2   = 64 KiB   @ 18 MiB
    //   bc  : 8192*4      = 32 KiB   @ 18 MiB + 64 KiB
    char* ws = (char*)d_ws;
    short* xb  = (short*)(ws);
    short* W1b = (short*)(ws + (size_t)16 * 1024 * 1024);
    short* Wcb = (short*)(ws + (size_t)18 * 1024 * 1024);
    float* bcv = (float*)(ws + (size_t)18 * 1024 * 1024 + 64 * 1024);

    convert_all<<<2048, 256, 0, stream>>>(x, W1, W2, W3, xb, W1b, Wcb);
    bc_mfma<<<M_ROWS / 64, 256, 0, stream>>>(xb, Wcb, b2, b3, bcv);
    dim3 grid(DM / 128, M_ROWS / 128);   // (8, 64) = 512 blocks
    gemm_fused<<<grid, 256, 0, stream>>>(xb, W1b, x, b1, bcv, out);
}

// Round 3
// 178.805 us; speedup vs baseline: 1.4738x; 1.1429x over previous
//
#include <hip/hip_runtime.h>
#include <hip/hip_bf16.h>
#include <cmath>

#define BATCH 4
#define SEQ 2048
#define DM 1024
#define NS 16
#define M_ROWS (BATCH * SEQ)

typedef short bf16x8 __attribute__((ext_vector_type(8)));
typedef short bf16x4 __attribute__((ext_vector_type(4)));
typedef float f32x4 __attribute__((ext_vector_type(4)));

// fp32 -> bf16 round-to-nearest-even
__device__ __forceinline__ short f2bf(float f) {
    union { float f; unsigned u; } a; a.f = f;
    unsigned u = a.u;
    return (short)((u + 0x7fffu + ((u >> 16) & 1u)) >> 16);
}
__device__ __forceinline__ float bf2f(unsigned short s) {
    union { unsigned u; float f; } a; a.u = ((unsigned)s) << 16;
    return a.f;
}

#define LDS_CAST(p) ((__attribute__((address_space(3))) unsigned*)(p))
#define GLB_CAST(p) ((const __attribute__((address_space(1))) unsigned*)(p))

// ---------------------------------------------------------------------------
// Kernel 0: convert x, W1, W2, W3 fp32 -> bf16. Segment chosen by blockIdx
// (no per-iteration branching). Each block: 256 thr x 4 float4 quads.
// Wcb = [W2(16 rows); W3(16 rows)], row-major, K contiguous.
// ---------------------------------------------------------------------------
__global__ void __launch_bounds__(256) convert_all(
    const float* __restrict__ x,  const float* __restrict__ W1,
    const float* __restrict__ W2, const float* __restrict__ W3,
    short* __restrict__ xb, short* __restrict__ W1b, short* __restrict__ Wcb)
{
    const int b = blockIdx.x;
    const int t = threadIdx.x;
    const float4* src; bf16x4* dst; int qbase;
    if (b < 2048)      { src = (const float4*)x;  dst = (bf16x4*)xb;  qbase = b * 1024; }
    else if (b < 2304) { src = (const float4*)W1; dst = (bf16x4*)W1b; qbase = (b - 2048) * 1024; }
    else if (b < 2308) { src = (const float4*)W2; dst = (bf16x4*)Wcb; qbase = (b - 2304) * 1024; }
    else               { src = (const float4*)W3; dst = (bf16x4*)(Wcb + NS * DM); qbase = (b - 2308) * 1024; }
    #pragma unroll
    for (int i = 0; i < 4; i++) {
        int q = qbase + i * 256 + t;
        float4 v = src[q];
        bf16x4 s;
        s.x = f2bf(v.x); s.y = f2bf(v.y); s.z = f2bf(v.z); s.w = f2bf(v.w);
        dst[q] = s;
    }
}

// ---------------------------------------------------------------------------
// Kernel 1: fused  z = xb @ W1b^T  (64x128 tile, BK=64, global_load_lds with
// global-side XOR swizzle),  bc = sum_n (B+b2)(C+b3) computed in-loop via Wc
// MFMA,  epilogue y = x * softplus(z+b1) * bc.
// LDS layout: As[row][chunk] holds global k-chunk (chunk ^ (row&7)); reads
// un-swizzle. Keeps global_load_lds's base+lane*16 LDS constraint AND makes
// ds_read_b128 2-way-max on banks (free per m136).
// ---------------------------------------------------------------------------
__global__ void __launch_bounds__(256) gemm_fused(
    const short* __restrict__ xb, const short* __restrict__ W1b,
    const short* __restrict__ Wcb, const float* __restrict__ b1,
    const float* __restrict__ b2,  const float* __restrict__ b3,
    float* __restrict__ out)
{
    __shared__ short As[64][64];     // 8 KB  x tile   [m][k]
    __shared__ short Bs[128][64];    // 16 KB W1 tile  [n][k]
    __shared__ short Wcs[32][64];    // 4 KB  Wc tile  [n][k]
    __shared__ float bcs[64];

    const int n0 = blockIdx.x * 128;
    const int m0 = blockIdx.y * 64;
    const int t = threadIdx.x;
    const int lane = t & 63;
    const int w = t >> 6;
    const int wm = (w >> 1) * 32;
    const int wn = (w & 1) * 64;
    const int lm = lane & 15;
    const int quad = lane >> 4;

    const int srow = t >> 3;        // 0..31 staging row within 32-row group
    const int schunk = t & 7;       // 0..7 staging 16B chunk

    f32x4 acc[2][4] = {};
    f32x4 abc[2] = {};

    for (int k0 = 0; k0 < DM; k0 += 64) {
        // ---- stage (global-side XOR swizzle: LDS[row][c] = glb[c^(row&7)]) ----
        #pragma unroll
        for (int u = 0; u < 2; u++) {
            int row = u * 32 + srow;
            int gch = schunk ^ (row & 7);
            const short* ga = xb + (size_t)(m0 + row) * DM + k0 + gch * 8;
            __builtin_amdgcn_global_load_lds(GLB_CAST(ga), LDS_CAST(&As[row][schunk * 8]), 16, 0, 0);
        }
        #pragma unroll
        for (int u = 0; u < 4; u++) {
            int row = u * 32 + srow;
            int gch = schunk ^ (row & 7);
            const short* gb = W1b + (size_t)(n0 + row) * DM + k0 + gch * 8;
            __builtin_amdgcn_global_load_lds(GLB_CAST(gb), LDS_CAST(&Bs[row][schunk * 8]), 16, 0, 0);
        }
        {
            int row = srow;
            int gch = schunk ^ (row & 7);
            const short* gw = Wcb + (size_t)row * DM + k0 + gch * 8;
            __builtin_amdgcn_global_load_lds(GLB_CAST(gw), LDS_CAST(&Wcs[row][schunk * 8]), 16, 0, 0);
        }
        __syncthreads();

        #pragma unroll
        for (int ks = 0; ks < 2; ks++) {
            const int g = ks * 4 + quad;   // logical 16B chunk for this quad
            bf16x8 af[2], bfv[4], wcv[2], ab;
            #pragma unroll
            for (int i = 0; i < 2; i++) {
                int r = wm + i * 16 + lm;
                af[i] = *(const bf16x8*)&As[r][(g ^ (r & 7)) * 8];
            }
            #pragma unroll
            for (int j = 0; j < 4; j++) {
                int r = wn + j * 16 + lm;
                bfv[j] = *(const bf16x8*)&Bs[r][(g ^ (r & 7)) * 8];
            }
            {
                int rb = w * 16 + lm;      // this wave's bc rows
                ab = *(const bf16x8*)&As[rb][(g ^ (rb & 7)) * 8];
            }
            #pragma unroll
            for (int jj = 0; jj < 2; jj++) {
                int r = jj * 16 + lm;
                wcv[jj] = *(const bf16x8*)&Wcs[r][(g ^ (r & 7)) * 8];
            }
            #pragma unroll
            for (int i = 0; i < 2; i++)
                #pragma unroll
                for (int j = 0; j < 4; j++)
                    acc[i][j] = __builtin_amdgcn_mfma_f32_16x16x32_bf16(
                        af[i], bfv[j], acc[i][j], 0, 0, 0);
            #pragma unroll
            for (int jj = 0; jj < 2; jj++)
                abc[jj] = __builtin_amdgcn_mfma_f32_16x16x32_bf16(
                    ab, wcv[jj], abc[jj], 0, 0, 0);
        }
        __syncthreads();
    }

    // ---- bc reduce: lane holds n=lm (abc[0]:W2, abc[1]:W3), row=w*16+quad*4+r
    float bb2 = b2[lm], bb3 = b3[lm];
    #pragma unroll
    for (int r = 0; r < 4; r++) {
        float p = (abc[0][r] + bb2) * (abc[1][r] + bb3);
        p += __shfl_xor(p, 1);
        p += __shfl_xor(p, 2);
        p += __shfl_xor(p, 4);
        p += __shfl_xor(p, 8);
        if (lm == 0) bcs[w * 16 + quad * 4 + r] = p;
    }
    __syncthreads();

    // ---- epilogue: D col(n)=lm, row(m)=quad*4+r ----
    const unsigned short* xbu = (const unsigned short*)xb;
    #pragma unroll
    for (int i = 0; i < 2; i++) {
        #pragma unroll
        for (int r = 0; r < 4; r++) {
            int lrow = wm + i * 16 + quad * 4 + r;
            int gm = m0 + lrow;
            float bcv = bcs[lrow];
            #pragma unroll
            for (int j = 0; j < 4; j++) {
                int gn = n0 + wn + j * 16 + lm;
                float z = acc[i][j][r] + b1[gn];
                float sp = (z > 0.f) ? z + log1pf(expf(-z)) : log1pf(expf(z));
                size_t idx = (size_t)gm * DM + gn;
                out[idx] = bf2f(xbu[idx]) * sp * bcv;
            }
        }
    }
}

extern "C" void kernel_launch(void* const* d_in, const int* in_sizes, int n_in,
                              void* d_out, int out_size, void* d_ws, size_t ws_size,
                              hipStream_t stream) {
    const float* x  = (const float*)d_in[0];
    const float* W1 = (const float*)d_in[1];
    const float* b1 = (const float*)d_in[2];
    const float* W2 = (const float*)d_in[3];
    const float* b2 = (const float*)d_in[4];
    const float* W3 = (const float*)d_in[5];
    const float* b3 = (const float*)d_in[6];
    // d_in[7] = A is dead math
    float* out = (float*)d_out;

    // ws: xb 16 MiB @0 | W1b 2 MiB @16M | Wcb 64 KiB @18M
    char* ws = (char*)d_ws;
    short* xb  = (short*)(ws);
    short* W1b = (short*)(ws + (size_t)16 * 1024 * 1024);
    short* Wcb = (short*)(ws + (size_t)18 * 1024 * 1024);

    convert_all<<<2312, 256, 0, stream>>>(x, W1, W2, W3, xb, W1b, Wcb);

    dim3 grid(DM / 128, M_ROWS / 64);   // (8, 128) = 1024 blocks = 4/CU
    gemm_fused<<<grid, 256, 0, stream>>>(xb, W1b, Wcb, b1, b2, b3, out);
}

// Round 5
// 127.994 us; speedup vs baseline: 2.0589x; 1.3970x over previous
//
#include <hip/hip_runtime.h>
#include <hip/hip_bf16.h>
#include <cmath>

#define BATCH 4
#define SEQ 2048
#define DM 1024
#define NS 16
#define M_ROWS (BATCH * SEQ)

typedef short bf16x8 __attribute__((ext_vector_type(8)));
typedef short bf16x4 __attribute__((ext_vector_type(4)));
typedef float f32x4 __attribute__((ext_vector_type(4)));

// fp32 -> bf16 round-to-nearest-even
__device__ __forceinline__ short f2bf(float f) {
    union { float f; unsigned u; } a; a.f = f;
    unsigned u = a.u;
    return (short)((u + 0x7fffu + ((u >> 16) & 1u)) >> 16);
}
__device__ __forceinline__ float bf2f(unsigned short s) {
    union { unsigned u; float f; } a; a.u = ((unsigned)s) << 16;
    return a.f;
}

#define LDS_CAST(p) ((__attribute__((address_space(3))) unsigned*)(p))
#define GLB_CAST(p) ((const __attribute__((address_space(1))) unsigned*)(p))

// ---------------------------------------------------------------------------
// Kernel 0: convert x, W1, W2, W3 fp32 -> bf16. Block-uniform segment select.
// Wcb = [W2(16 rows); W3(16 rows)], row-major, K contiguous.  (~15 us)
// ---------------------------------------------------------------------------
__global__ void __launch_bounds__(256) convert_all(
    const float* __restrict__ x,  const float* __restrict__ W1,
    const float* __restrict__ W2, const float* __restrict__ W3,
    short* __restrict__ xb, short* __restrict__ W1b, short* __restrict__ Wcb)
{
    const int b = blockIdx.x;
    const int t = threadIdx.x;
    const float4* src; bf16x4* dst; int qbase;
    if (b < 2048)      { src = (const float4*)x;  dst = (bf16x4*)xb;  qbase = b * 1024; }
    else if (b < 2304) { src = (const float4*)W1; dst = (bf16x4*)W1b; qbase = (b - 2048) * 1024; }
    else if (b < 2308) { src = (const float4*)W2; dst = (bf16x4*)Wcb; qbase = (b - 2304) * 1024; }
    else               { src = (const float4*)W3; dst = (bf16x4*)(Wcb + NS * DM); qbase = (b - 2308) * 1024; }
    #pragma unroll
    for (int i = 0; i < 4; i++) {
        int q = qbase + i * 256 + t;
        float4 v = src[q];
        bf16x4 s;
        s.x = f2bf(v.x); s.y = f2bf(v.y); s.z = f2bf(v.z); s.w = f2bf(v.w);
        dst[q] = s;
    }
}

// ---------------------------------------------------------------------------
// Kernel 1: fused  z = xb @ W1b^T  (64x128 tile, BK=64, fully-unrolled K,
// global_load_lds w/ global-side XOR swizzle),  bc = sum_n (B+b2)(C+b3)
// in-loop via Wc MFMA,  epilogue y = x * softplus(z+b1) * bc (fast softplus).
// K-advance is folded into the staging POINTER with a constant (kk*64) per
// unrolled iteration; intrinsic offset arg stays literal 0 (frontend
// requires ICE) and ISel folds the constant add into the 13-bit imm field.
// ---------------------------------------------------------------------------
__global__ void __launch_bounds__(256) gemm_fused(
    const short* __restrict__ xb, const short* __restrict__ W1b,
    const short* __restrict__ Wcb, const float* __restrict__ b1,
    const float* __restrict__ b2,  const float* __restrict__ b3,
    float* __restrict__ out)
{
    __shared__ short As[64][64];     // 8 KB  x tile   [m][k]
    __shared__ short Bs[128][64];    // 16 KB W1 tile  [n][k]
    __shared__ short Wcs[32][64];    // 4 KB  Wc tile  [n][k]
    __shared__ float bcs[64];

    const int n0 = blockIdx.x * 128;
    const int m0 = blockIdx.y * 64;
    const int t = threadIdx.x;
    const int lane = t & 63;
    const int w = t >> 6;
    const int wm = (w >> 1) * 32;
    const int wn = (w & 1) * 64;
    const int lm = lane & 15;
    const int quad = lane >> 4;

    const int srow = t >> 3;              // 0..31
    const int schunk = t & 7;             // 0..7
    const int gch = (schunk ^ (srow & 7)) * 8;   // swizzled k-element offset

    // loop-invariant staging pointers (kk*64 added as a constant per iter)
    const short* pa0 = xb  + (size_t)(m0 + srow)      * DM + gch;
    const short* pa1 = xb  + (size_t)(m0 + 32 + srow) * DM + gch;
    const short* pb0 = W1b + (size_t)(n0 + srow)      * DM + gch;
    const short* pb1 = W1b + (size_t)(n0 + 32 + srow) * DM + gch;
    const short* pb2 = W1b + (size_t)(n0 + 64 + srow) * DM + gch;
    const short* pb3 = W1b + (size_t)(n0 + 96 + srow) * DM + gch;
    const short* pw  = Wcb + (size_t)srow             * DM + gch;

    f32x4 acc[2][4] = {};
    f32x4 abc[2] = {};

    #pragma unroll
    for (int kk = 0; kk < 16; kk++) {
        const int ke = kk * 64;          // element offset, constant per iter
        __builtin_amdgcn_global_load_lds(GLB_CAST(pa0 + ke), LDS_CAST(&As[srow][schunk * 8]),      16, 0, 0);
        __builtin_amdgcn_global_load_lds(GLB_CAST(pa1 + ke), LDS_CAST(&As[32 + srow][schunk * 8]), 16, 0, 0);
        __builtin_amdgcn_global_load_lds(GLB_CAST(pb0 + ke), LDS_CAST(&Bs[srow][schunk * 8]),      16, 0, 0);
        __builtin_amdgcn_global_load_lds(GLB_CAST(pb1 + ke), LDS_CAST(&Bs[32 + srow][schunk * 8]), 16, 0, 0);
        __builtin_amdgcn_global_load_lds(GLB_CAST(pb2 + ke), LDS_CAST(&Bs[64 + srow][schunk * 8]), 16, 0, 0);
        __builtin_amdgcn_global_load_lds(GLB_CAST(pb3 + ke), LDS_CAST(&Bs[96 + srow][schunk * 8]), 16, 0, 0);
        __builtin_amdgcn_global_load_lds(GLB_CAST(pw  + ke), LDS_CAST(&Wcs[srow][schunk * 8]),     16, 0, 0);
        __syncthreads();

        #pragma unroll
        for (int ks = 0; ks < 2; ks++) {
            const int g = ks * 4 + quad;   // logical 16B chunk for this quad
            bf16x8 af[2], bfv[4], wcv[2], ab;
            #pragma unroll
            for (int i = 0; i < 2; i++) {
                int r = wm + i * 16 + lm;
                af[i] = *(const bf16x8*)&As[r][(g ^ (r & 7)) * 8];
            }
            #pragma unroll
            for (int j = 0; j < 4; j++) {
                int r = wn + j * 16 + lm;
                bfv[j] = *(const bf16x8*)&Bs[r][(g ^ (r & 7)) * 8];
            }
            {
                int rb = w * 16 + lm;      // this wave's bc rows
                ab = *(const bf16x8*)&As[rb][(g ^ (rb & 7)) * 8];
            }
            #pragma unroll
            for (int jj = 0; jj < 2; jj++) {
                int r = jj * 16 + lm;
                wcv[jj] = *(const bf16x8*)&Wcs[r][(g ^ (r & 7)) * 8];
            }
            #pragma unroll
            for (int i = 0; i < 2; i++)
                #pragma unroll
                for (int j = 0; j < 4; j++)
                    acc[i][j] = __builtin_amdgcn_mfma_f32_16x16x32_bf16(
                        af[i], bfv[j], acc[i][j], 0, 0, 0);
            #pragma unroll
            for (int jj = 0; jj < 2; jj++)
                abc[jj] = __builtin_amdgcn_mfma_f32_16x16x32_bf16(
                    ab, wcv[jj], abc[jj], 0, 0, 0);
        }
        __syncthreads();
    }

    // ---- bc reduce: lane holds n=lm (abc[0]:W2, abc[1]:W3), row=w*16+quad*4+r
    float bb2 = b2[lm], bb3 = b3[lm];
    #pragma unroll
    for (int r = 0; r < 4; r++) {
        float p = (abc[0][r] + bb2) * (abc[1][r] + bb3);
        p += __shfl_xor(p, 1);
        p += __shfl_xor(p, 2);
        p += __shfl_xor(p, 4);
        p += __shfl_xor(p, 8);
        if (lm == 0) bcs[w * 16 + quad * 4 + r] = p;
    }
    __syncthreads();

    // ---- epilogue: D col(n)=lm, row(m)=quad*4+r; fast stable softplus ----
    const unsigned short* xbu = (const unsigned short*)xb;
    float b1v[4];
    #pragma unroll
    for (int j = 0; j < 4; j++) b1v[j] = b1[n0 + wn + j * 16 + lm];

    #pragma unroll
    for (int i = 0; i < 2; i++) {
        #pragma unroll
        for (int r = 0; r < 4; r++) {
            int lrow = wm + i * 16 + quad * 4 + r;
            int gm = m0 + lrow;
            float bcv = bcs[lrow];
            const unsigned short* xrow = xbu + (size_t)gm * DM + n0 + wn + lm;
            float* orow = out + (size_t)gm * DM + n0 + wn + lm;
            #pragma unroll
            for (int j = 0; j < 4; j++) {
                float z = acc[i][j][r] + b1v[j];
                float az = __builtin_fabsf(z);
                float sp = fmaxf(z, 0.f) + __logf(1.f + __expf(-az));
                orow[j * 16] = bf2f(xrow[j * 16]) * sp * bcv;
            }
        }
    }
}

extern "C" void kernel_launch(void* const* d_in, const int* in_sizes, int n_in,
                              void* d_out, int out_size, void* d_ws, size_t ws_size,
                              hipStream_t stream) {
    const float* x  = (const float*)d_in[0];
    const float* W1 = (const float*)d_in[1];
    const float* b1 = (const float*)d_in[2];
    const float* W2 = (const float*)d_in[3];
    const float* b2 = (const float*)d_in[4];
    const float* W3 = (const float*)d_in[5];
    const float* b3 = (const float*)d_in[6];
    // d_in[7] = A is dead math
    float* out = (float*)d_out;

    // ws: xb 16 MiB @0 | W1b 2 MiB @16M | Wcb 64 KiB @18M
    char* ws = (char*)d_ws;
    short* xb  = (short*)(ws);
    short* W1b = (short*)(ws + (size_t)16 * 1024 * 1024);
    short* Wcb = (short*)(ws + (size_t)18 * 1024 * 1024);

    convert_all<<<2312, 256, 0, stream>>>(x, W1, W2, W3, xb, W1b, Wcb);

    dim3 grid(DM / 128, M_ROWS / 64);   // (8, 128) = 1024 blocks = 4/CU
    gemm_fused<<<grid, 256, 0, stream>>>(xb, W1b, Wcb, b1, b2, b3, out);
}